// Round 2
// baseline (975.904 us; speedup 1.0000x reference)
//
#include <hip/hip_runtime.h>

#define L_ 13
#define B_ 32
#define S_ 128
#define H_ 768
#define NU 32
#define GG 64
#define TU 96
#define LN_EPS 1e-3f

__device__ __forceinline__ float sigmoidf_(float a) { return 1.0f / (1.0f + __expf(-a)); }
__device__ __forceinline__ float tanhf_(float a) { float e = __expf(-2.0f * a); return (1.0f - e) / (1.0f + e); }

// ---------------- lin_all = xs @ W_lin + b_lin for ALL 13 layers (fully parallel) ----------------
__global__ __launch_bounds__(256) void lin_kernel(
    const float* __restrict__ xs, const float* __restrict__ Wl,
    const float* __restrict__ bl, float* __restrict__ lin)
{
    __shared__ float sA[64][68];
    __shared__ float sW[64][68];
    const int t = threadIdx.x;
    const size_t row0 = (size_t)blockIdx.x * 64;
    const int r4 = (t >> 4) << 2;   // 4 rows per thread
    const int c4 = (t & 15) << 2;   // 4 cols per thread

    float acc[4][4];
    #pragma unroll
    for (int i = 0; i < 4; ++i)
        #pragma unroll
        for (int j = 0; j < 4; ++j) acc[i][j] = 0.f;

    for (int kt = 0; kt < H_; kt += 64) {
        #pragma unroll
        for (int p = 0; p < 4; ++p) {
            int idx = t + 256 * p;                 // 1024 float4 slots
            int r = idx >> 4, cc = (idx & 15) << 2;
            *(float4*)&sA[r][cc] = *(const float4*)&xs[(row0 + r) * H_ + kt + cc];
            *(float4*)&sW[r][cc] = *(const float4*)&Wl[(size_t)(kt + r) * GG + cc];
        }
        __syncthreads();
        #pragma unroll 8
        for (int k = 0; k < 64; ++k) {
            float a0 = sA[r4 + 0][k], a1 = sA[r4 + 1][k], a2 = sA[r4 + 2][k], a3 = sA[r4 + 3][k];
            float4 w = *(const float4*)&sW[k][c4];
            acc[0][0] += a0 * w.x; acc[0][1] += a0 * w.y; acc[0][2] += a0 * w.z; acc[0][3] += a0 * w.w;
            acc[1][0] += a1 * w.x; acc[1][1] += a1 * w.y; acc[1][2] += a1 * w.z; acc[1][3] += a1 * w.w;
            acc[2][0] += a2 * w.x; acc[2][1] += a2 * w.y; acc[2][2] += a2 * w.z; acc[2][3] += a2 * w.w;
            acc[3][0] += a3 * w.x; acc[3][1] += a3 * w.y; acc[3][2] += a3 * w.z; acc[3][3] += a3 * w.w;
        }
        __syncthreads();
    }
    float4 bv = *(const float4*)&bl[c4];
    #pragma unroll
    for (int i = 0; i < 4; ++i) {
        float4 o = make_float4(acc[i][0] + bv.x, acc[i][1] + bv.y, acc[i][2] + bv.z, acc[i][3] + bv.w);
        *(float4*)&lin[(row0 + r4 + i) * GG + c4] = o;
    }
}

// ---------------- persistent per-(dir,batch) chain: 13 x (LN + xp + GRU scan) + classifier ----------------
__global__ __launch_bounds__(256) void chain_kernel(
    const float* __restrict__ lin_all,
    const float* __restrict__ Wr_f, const float* __restrict__ b_f,
    const float* __restrict__ Wr_b, const float* __restrict__ b_b,
    const float* __restrict__ Wk_f, const float* __restrict__ Wk_b,
    const float* __restrict__ ln_g, const float* __restrict__ ln_b,
    const float* __restrict__ W_cls, const float* __restrict__ b_cls,
    float* __restrict__ seq0, float* __restrict__ seq1,
    float* __restrict__ hbuf, unsigned int* __restrict__ flags,
    float* __restrict__ out)
{
    const int dir = blockIdx.x & 1;
    const int b   = blockIdx.x >> 1;
    const int t = threadIdx.x;
    const int wave = t >> 6;
    const int lane = t & 63;
    const int u = lane & 31;
    const int half = lane >> 5;

    __shared__ float xp[S_][100];    // padded vs bank conflicts
    __shared__ float sX[32][68];
    __shared__ float hb[NU];

    const float* Wk   = dir ? Wk_b : Wk_f;
    const float* Wr   = dir ? Wr_b : Wr_f;
    const float* bias = dir ? b_b  : b_f;

    // scan-wave persistent registers
    float wz[16], wr_[16], wh[16], hreg[16];
    float h_own = 0.f;
    if (wave == 0) {
        #pragma unroll
        for (int jj = 0; jj < 16; ++jj) {
            int j = half * 16 + jj;
            wz[jj]  = Wr[j * TU + u];
            wr_[jj] = Wr[j * TU + NU + u];
            wh[jj]  = Wr[j * TU + 2 * NU + u];
            hreg[jj] = 0.f;
        }
    }
    const float rbz = bias[TU + u], rbr = bias[TU + NU + u], rbh = bias[TU + 2 * NU + u];

    for (int l = 0; l < L_; ++l) {
        const float* seqr = (l & 1) ? seq0 : seq1;   // read buffer (written by layer l-1)
        float*       seqw = (l & 1) ? seq1 : seq0;   // write buffer

        if (l > 0) {
            if (t == 0) {
                const unsigned target = 2u * (unsigned)l;
                int guard = 0;
                while (__hip_atomic_load(&flags[b], __ATOMIC_ACQUIRE, __HIP_MEMORY_SCOPE_AGENT) < target) {
                    if (++guard > (1 << 27)) break;
                }
            }
            __syncthreads();
            (void)__hip_atomic_load(&flags[b], __ATOMIC_ACQUIRE, __HIP_MEMORY_SCOPE_AGENT);
        }

        const float* linb = lin_all + ((size_t)l * (B_ * S_) + (size_t)b * S_) * GG;

        // ---- prologue: x = LN(lin + seq); xp = x @ Wk + bias0  (4 chunks of 32 rows) ----
        for (int ch = 0; ch < 4; ++ch) {
            #pragma unroll
            for (int pass = 0; pass < 2; ++pass) {
                const int rloc = wave * 4 + (lane >> 4) + pass * 16;
                const int row = ch * 32 + rloc;
                const int c = (lane & 15) << 2;
                float4 v = *(const float4*)&linb[(size_t)row * GG + c];
                if (l > 0) {
                    float4 sq = *(const float4*)&seqr[((size_t)b * S_ + row) * GG + c];
                    v.x += sq.x; v.y += sq.y; v.z += sq.z; v.w += sq.w;
                }
                float s = v.x + v.y + v.z + v.w;
                #pragma unroll
                for (int off = 1; off < 16; off <<= 1) s += __shfl_xor(s, off);
                const float mean = s * 0.015625f;
                const float d0 = v.x - mean, d1 = v.y - mean, d2 = v.z - mean, d3 = v.w - mean;
                float q = d0 * d0 + d1 * d1 + d2 * d2 + d3 * d3;
                #pragma unroll
                for (int off = 1; off < 16; off <<= 1) q += __shfl_xor(q, off);
                const float rstd = rsqrtf(q * 0.015625f + LN_EPS);
                float4 g  = *(const float4*)&ln_g[c];
                float4 bt = *(const float4*)&ln_b[c];
                float4 xo = make_float4(d0 * rstd * g.x + bt.x, d1 * rstd * g.y + bt.y,
                                        d2 * rstd * g.z + bt.z, d3 * rstd * g.w + bt.w);
                *(float4*)&sX[rloc][c] = xo;
            }
            __syncthreads();
            {
                const int rloc = t & 31;
                const int cc = (t >> 5) * 12;
                float a[12];
                #pragma unroll
                for (int m = 0; m < 12; ++m) a[m] = bias[cc + m];
                #pragma unroll 4
                for (int k = 0; k < GG; ++k) {
                    const float xv = sX[rloc][k];
                    float4 wA = *(const float4*)&Wk[k * TU + cc];
                    float4 wB = *(const float4*)&Wk[k * TU + cc + 4];
                    float4 wC = *(const float4*)&Wk[k * TU + cc + 8];
                    a[0] += xv * wA.x; a[1] += xv * wA.y; a[2]  += xv * wA.z; a[3]  += xv * wA.w;
                    a[4] += xv * wB.x; a[5] += xv * wB.y; a[6]  += xv * wB.z; a[7]  += xv * wB.w;
                    a[8] += xv * wC.x; a[9] += xv * wC.y; a[10] += xv * wC.z; a[11] += xv * wC.w;
                }
                const int row = ch * 32 + rloc;
                *(float4*)&xp[row][cc + 0] = make_float4(a[0], a[1], a[2], a[3]);
                *(float4*)&xp[row][cc + 4] = make_float4(a[4], a[5], a[6], a[7]);
                *(float4*)&xp[row][cc + 8] = make_float4(a[8], a[9], a[10], a[11]);
            }
            __syncthreads();
        }

        // ---- scan (wave 0 only; in-wave sync only) ----
        if (wave == 0) {
            float* seqo = seqw + ((size_t)b * S_) * GG + NU * dir + u;
            for (int st = 0; st < S_; ++st) {
                const int s = dir ? (S_ - 1 - st) : st;
                const float xz = xp[s][u], xr = xp[s][NU + u], xh = xp[s][2 * NU + u];
                float rz0 = 0.f, rz1 = 0.f, rr0 = 0.f, rr1 = 0.f, rh0 = 0.f, rh1 = 0.f;
                #pragma unroll
                for (int jj = 0; jj < 16; jj += 2) {
                    rz0 += hreg[jj] * wz[jj];    rz1 += hreg[jj + 1] * wz[jj + 1];
                    rr0 += hreg[jj] * wr_[jj];   rr1 += hreg[jj + 1] * wr_[jj + 1];
                    rh0 += hreg[jj] * wh[jj];    rh1 += hreg[jj + 1] * wh[jj + 1];
                }
                float rz = rz0 + rz1, rr = rr0 + rr1, rh = rh0 + rh1;
                rz += __shfl_xor(rz, 32);
                rr += __shfl_xor(rr, 32);
                rh += __shfl_xor(rh, 32);
                const float z  = sigmoidf_(xz + rz + rbz);
                const float r  = sigmoidf_(xr + rr + rbr);
                const float hh = tanhf_(xh + r * (rh + rbh));
                const float hn = hh + z * (h_own - hh);
                if (half == 0) {
                    hb[u] = hn;
                    seqo[(size_t)s * GG] = hn;
                }
                #pragma unroll
                for (int q2 = 0; q2 < 4; ++q2) {
                    float4 hv = *(const float4*)&hb[half * 16 + q2 * 4];
                    hreg[q2 * 4 + 0] = hv.x; hreg[q2 * 4 + 1] = hv.y;
                    hreg[q2 * 4 + 2] = hv.z; hreg[q2 * 4 + 3] = hv.w;
                }
                h_own = hn;
            }
            __threadfence();
            if (lane == 0)
                __hip_atomic_fetch_add(&flags[b], 1u, __ATOMIC_RELEASE, __HIP_MEMORY_SCOPE_AGENT);
        }
        __syncthreads();
    }

    // ---- final h + fused classifier ----
    if (wave == 0 && half == 0)
        hbuf[((size_t)dir * B_ + b) * NU + u] = h_own;
    if (wave == 0) {
        __threadfence();
        if (lane == 0)
            __hip_atomic_fetch_add(&flags[64 + b], 1u, __ATOMIC_RELEASE, __HIP_MEMORY_SCOPE_AGENT);
    }
    if (dir == 0) {
        if (t == 0) {
            int guard = 0;
            while (__hip_atomic_load(&flags[64 + b], __ATOMIC_ACQUIRE, __HIP_MEMORY_SCOPE_AGENT) < 2u) {
                if (++guard > (1 << 27)) break;
            }
        }
        __syncthreads();
        if (t == 0) {
            (void)__hip_atomic_load(&flags[64 + b], __ATOMIC_ACQUIRE, __HIP_MEMORY_SCOPE_AGENT);
            float l0 = b_cls[0], l1 = b_cls[1];
            for (int j = 0; j < NU; ++j) {
                const float hf = hbuf[(size_t)b * NU + j];          // fwd
                const float hk = hbuf[(size_t)(B_ + b) * NU + j];   // bwd
                l0 += hf * W_cls[(2 * j) * 2 + 0] + hk * W_cls[(2 * j + 1) * 2 + 0];
                l1 += hf * W_cls[(2 * j) * 2 + 1] + hk * W_cls[(2 * j + 1) * 2 + 1];
            }
            const float m = fmaxf(l0, l1);
            const float e0 = __expf(l0 - m), e1 = __expf(l1 - m);
            const float inv = 1.0f / (e0 + e1);
            out[b * 2 + 0] = e0 * inv;
            out[b * 2 + 1] = e1 * inv;
        }
    }
}

extern "C" void kernel_launch(void* const* d_in, const int* in_sizes, int n_in,
                              void* d_out, int out_size, void* d_ws, size_t ws_size,
                              hipStream_t stream) {
    const float* xs    = (const float*)d_in[0];
    const float* W_lin = (const float*)d_in[1];
    const float* b_lin = (const float*)d_in[2];
    const float* ln_g  = (const float*)d_in[3];
    const float* ln_b  = (const float*)d_in[4];
    const float* Wk_f  = (const float*)d_in[5];
    const float* Wr_f  = (const float*)d_in[6];
    const float* b_f   = (const float*)d_in[7];
    const float* Wk_b  = (const float*)d_in[8];
    const float* Wr_b  = (const float*)d_in[9];
    const float* b_b   = (const float*)d_in[10];
    const float* W_cls = (const float*)d_in[11];
    const float* b_cls = (const float*)d_in[12];
    float* out = (float*)d_out;

    char* ws = (char*)d_ws;
    float* lin_all = (float*)(ws);                                   // 13*4096*64*4 = 13,631,488 B
    float* seq0    = (float*)(ws + 13631488);                        // 1,048,576 B
    float* seq1    = (float*)(ws + 13631488 + 1048576);              // 1,048,576 B
    float* hbuf    = (float*)(ws + 13631488 + 2 * 1048576);          // 8,192 B
    unsigned int* flags = (unsigned int*)(ws + 13631488 + 2 * 1048576 + 8192);  // 512 B

    hipMemsetAsync(flags, 0, 512, stream);

    lin_kernel<<<(L_ * B_ * S_) / 64, 256, 0, stream>>>(xs, W_lin, b_lin, lin_all);

    chain_kernel<<<64, 256, 0, stream>>>(
        lin_all, Wr_f, b_f, Wr_b, b_b, Wk_f, Wk_b, ln_g, ln_b, W_cls, b_cls,
        seq0, seq1, hbuf, flags, out);
}

// Round 3
// 710.920 us; speedup vs baseline: 1.3727x; 1.3727x over previous
//
#include <hip/hip_runtime.h>

#define L_ 13
#define B_ 32
#define S_ 128
#define H_ 768
#define NU 32
#define GG 64
#define TU 96
#define LN_EPS 1e-3f
#define SEQ_ST 68     // seq LDS row stride (floats) — breaks bank aliasing
#define XP_ST 100     // xp LDS row stride (floats)

typedef float v2f __attribute__((ext_vector_type(2)));

__device__ __forceinline__ float sigmoidf_(float a) { return 1.0f / (1.0f + __expf(-a)); }
__device__ __forceinline__ float tanhf_(float a) { float e = __expf(-2.0f * a); return (1.0f - e) / (1.0f + e); }
__device__ __forceinline__ void pkfma(v2f& a, v2f x, v2f w) {
    // packed fp32: 2 FMAs / instruction (gfx950 double-rate FP32)
    asm("v_pk_fma_f32 %0, %1, %2, %0" : "+v"(a) : "v"(x), "v"(w));
}

// ---------------- lin_all = xs @ W_lin + b_lin for ALL 13 layers (fully parallel) ----------------
__global__ __launch_bounds__(256) void lin_kernel(
    const float* __restrict__ xs, const float* __restrict__ Wl,
    const float* __restrict__ bl, float* __restrict__ lin)
{
    __shared__ float sA[64][68];
    __shared__ float sW[64][68];
    const int t = threadIdx.x;
    const size_t row0 = (size_t)blockIdx.x * 64;
    const int r4 = (t >> 4) << 2;
    const int c4 = (t & 15) << 2;

    float acc[4][4];
    #pragma unroll
    for (int i = 0; i < 4; ++i)
        #pragma unroll
        for (int j = 0; j < 4; ++j) acc[i][j] = 0.f;

    for (int kt = 0; kt < H_; kt += 64) {
        #pragma unroll
        for (int p = 0; p < 4; ++p) {
            int idx = t + 256 * p;
            int r = idx >> 4, cc = (idx & 15) << 2;
            *(float4*)&sA[r][cc] = *(const float4*)&xs[(row0 + r) * H_ + kt + cc];
            *(float4*)&sW[r][cc] = *(const float4*)&Wl[(size_t)(kt + r) * GG + cc];
        }
        __syncthreads();
        #pragma unroll 8
        for (int k = 0; k < 64; ++k) {
            float a0 = sA[r4 + 0][k], a1 = sA[r4 + 1][k], a2 = sA[r4 + 2][k], a3 = sA[r4 + 3][k];
            float4 w = *(const float4*)&sW[k][c4];
            acc[0][0] += a0 * w.x; acc[0][1] += a0 * w.y; acc[0][2] += a0 * w.z; acc[0][3] += a0 * w.w;
            acc[1][0] += a1 * w.x; acc[1][1] += a1 * w.y; acc[1][2] += a1 * w.z; acc[1][3] += a1 * w.w;
            acc[2][0] += a2 * w.x; acc[2][1] += a2 * w.y; acc[2][2] += a2 * w.z; acc[2][3] += a2 * w.w;
            acc[3][0] += a3 * w.x; acc[3][1] += a3 * w.y; acc[3][2] += a3 * w.z; acc[3][3] += a3 * w.w;
        }
        __syncthreads();
    }
    float4 bv = *(const float4*)&bl[c4];
    #pragma unroll
    for (int i = 0; i < 4; ++i) {
        float4 o = make_float4(acc[i][0] + bv.x, acc[i][1] + bv.y, acc[i][2] + bv.z, acc[i][3] + bv.w);
        *(float4*)&lin[(row0 + r4 + i) * GG + c4] = o;
    }
}

// ---------------- one block per batch: 13 x (LN + xp + bidir GRU scan) + classifier, all in LDS ----------------
__global__ __launch_bounds__(512) void chain_kernel(
    const float* __restrict__ lin_all,
    const float* __restrict__ Wr_f, const float* __restrict__ b_f,
    const float* __restrict__ Wr_b, const float* __restrict__ b_b,
    const float* __restrict__ Wk_f, const float* __restrict__ Wk_b,
    const float* __restrict__ ln_g, const float* __restrict__ ln_b,
    const float* __restrict__ W_cls, const float* __restrict__ b_cls,
    float* __restrict__ out)
{
    extern __shared__ float sm[];
    float* seqb = sm;                        // [128][SEQ_ST]  (x in-place, then GRU outputs)
    float* xpf  = sm + S_ * SEQ_ST;          // [128][XP_ST]
    float* xpb  = xpf + S_ * XP_ST;          // [128][XP_ST]
    float* hbf  = xpb + S_ * XP_ST;          // [32] fwd h broadcast
    float* hbb  = hbf + NU;                  // [32] bwd h broadcast

    const int b = blockIdx.x;
    const int t = threadIdx.x;
    const int wave = t >> 6;
    const int lane = t & 63;
    const int u = lane & 31;
    const int half = lane >> 5;

    for (int i = t; i < S_ * SEQ_ST; i += 512) seqb[i] = 0.f;

    // ---- scan-wave persistent state (waves 0=fwd, 1=bwd), kept across all 13 layers ----
    v2f wz2[8], wr2[8], wh2[8], h2r[8];
    float h_own = 0.f, rbz = 0.f, rbr = 0.f, rbh = 0.f;
    if (wave < 2) {
        const float* Wr   = wave ? Wr_b : Wr_f;
        const float* bias = wave ? b_b  : b_f;
        #pragma unroll
        for (int jj = 0; jj < 8; ++jj) {
            int j = half * 16 + 2 * jj;
            wz2[jj] = v2f{ Wr[j * TU + u],          Wr[(j + 1) * TU + u] };
            wr2[jj] = v2f{ Wr[j * TU + NU + u],     Wr[(j + 1) * TU + NU + u] };
            wh2[jj] = v2f{ Wr[j * TU + 2 * NU + u], Wr[(j + 1) * TU + 2 * NU + u] };
            h2r[jj] = v2f{ 0.f, 0.f };
        }
        rbz = bias[TU + u]; rbr = bias[TU + NU + u]; rbh = bias[TU + 2 * NU + u];
    }

    // LN mapping: 32 groups of 16 lanes, 4 rows each
    const int g = t >> 4;
    const int c4 = (t & 15) << 2;
    // xp mapping: 32 row-groups x 16 col-groups (12 cols each over [xp_f|xp_b])
    const int rgrp = t & 31;
    const int cg = t >> 5;
    const int dsel = cg >> 3;
    const int cc = (cg & 7) * 12;
    const float* WkX   = dsel ? Wk_b : Wk_f;
    const float* bias0 = dsel ? b_b  : b_f;
    float* xpX = dsel ? xpb : xpf;

    __syncthreads();

    for (int l = 0; l < L_; ++l) {
        const float* linb = lin_all + ((size_t)(l * B_ + b) * S_) * GG;

        // ---- phase 1: x = LN(lin + seq) in-place into seqb ----
        #pragma unroll
        for (int p = 0; p < 4; ++p) {
            const int r = g + 32 * p;
            float4 lv = *(const float4*)&linb[(size_t)r * GG + c4];
            float4 sv = *(const float4*)&seqb[r * SEQ_ST + c4];
            float v0 = lv.x + sv.x, v1 = lv.y + sv.y, v2 = lv.z + sv.z, v3 = lv.w + sv.w;
            float s = v0 + v1 + v2 + v3;
            #pragma unroll
            for (int off = 1; off < 16; off <<= 1) s += __shfl_xor(s, off);
            const float mean = s * 0.015625f;
            const float d0 = v0 - mean, d1 = v1 - mean, d2 = v2 - mean, d3 = v3 - mean;
            float q = d0 * d0 + d1 * d1 + d2 * d2 + d3 * d3;
            #pragma unroll
            for (int off = 1; off < 16; off <<= 1) q += __shfl_xor(q, off);
            const float rstd = rsqrtf(q * 0.015625f + LN_EPS);
            float4 gm = *(const float4*)&ln_g[c4];
            float4 bt = *(const float4*)&ln_b[c4];
            *(float4*)&seqb[r * SEQ_ST + c4] =
                make_float4(d0 * rstd * gm.x + bt.x, d1 * rstd * gm.y + bt.y,
                            d2 * rstd * gm.z + bt.z, d3 * rstd * gm.w + bt.w);
        }
        __syncthreads();

        // ---- phase 2: xp = x @ Wk + bias0 (packed fp32) ----
        {
            v2f acc[4][6];
            #pragma unroll
            for (int m = 0; m < 6; ++m) {
                v2f bi = v2f{ bias0[cc + 2 * m], bias0[cc + 2 * m + 1] };
                acc[0][m] = bi; acc[1][m] = bi; acc[2][m] = bi; acc[3][m] = bi;
            }
            #pragma unroll 4
            for (int k = 0; k < GG; ++k) {
                float x0 = seqb[rgrp * SEQ_ST + k];
                float x1 = seqb[(rgrp + 32) * SEQ_ST + k];
                float x2 = seqb[(rgrp + 64) * SEQ_ST + k];
                float x3 = seqb[(rgrp + 96) * SEQ_ST + k];
                float4 wA = *(const float4*)&WkX[k * TU + cc];
                float4 wB = *(const float4*)&WkX[k * TU + cc + 4];
                float4 wC = *(const float4*)&WkX[k * TU + cc + 8];
                v2f w0 = v2f{wA.x, wA.y}, w1 = v2f{wA.z, wA.w};
                v2f w2 = v2f{wB.x, wB.y}, w3 = v2f{wB.z, wB.w};
                v2f w4 = v2f{wC.x, wC.y}, w5 = v2f{wC.z, wC.w};
                v2f xx;
                xx = v2f{x0, x0};
                pkfma(acc[0][0], xx, w0); pkfma(acc[0][1], xx, w1); pkfma(acc[0][2], xx, w2);
                pkfma(acc[0][3], xx, w3); pkfma(acc[0][4], xx, w4); pkfma(acc[0][5], xx, w5);
                xx = v2f{x1, x1};
                pkfma(acc[1][0], xx, w0); pkfma(acc[1][1], xx, w1); pkfma(acc[1][2], xx, w2);
                pkfma(acc[1][3], xx, w3); pkfma(acc[1][4], xx, w4); pkfma(acc[1][5], xx, w5);
                xx = v2f{x2, x2};
                pkfma(acc[2][0], xx, w0); pkfma(acc[2][1], xx, w1); pkfma(acc[2][2], xx, w2);
                pkfma(acc[2][3], xx, w3); pkfma(acc[2][4], xx, w4); pkfma(acc[2][5], xx, w5);
                xx = v2f{x3, x3};
                pkfma(acc[3][0], xx, w0); pkfma(acc[3][1], xx, w1); pkfma(acc[3][2], xx, w2);
                pkfma(acc[3][3], xx, w3); pkfma(acc[3][4], xx, w4); pkfma(acc[3][5], xx, w5);
            }
            #pragma unroll
            for (int i = 0; i < 4; ++i) {
                const int r = rgrp + 32 * i;
                *(float4*)&xpX[r * XP_ST + cc]     = make_float4(acc[i][0].x, acc[i][0].y, acc[i][1].x, acc[i][1].y);
                *(float4*)&xpX[r * XP_ST + cc + 4] = make_float4(acc[i][2].x, acc[i][2].y, acc[i][3].x, acc[i][3].y);
                *(float4*)&xpX[r * XP_ST + cc + 8] = make_float4(acc[i][4].x, acc[i][4].y, acc[i][5].x, acc[i][5].y);
            }
        }
        __syncthreads();

        // ---- phase 3: fwd (wave 0) and bwd (wave 1) scans run concurrently on their own SIMDs ----
        if (wave < 2) {
            const int dir = wave;
            const float* xp = dir ? xpb : xpf;
            float* hb = dir ? hbb : hbf;
            int s = dir ? (S_ - 1) : 0;
            const int stp = dir ? -1 : 1;
            float xz = xp[s * XP_ST + u], xr = xp[s * XP_ST + NU + u], xh = xp[s * XP_ST + 2 * NU + u];
            for (int st = 0; st < S_; ++st) {
                float nz = 0.f, nr = 0.f, nh = 0.f;
                if (st < S_ - 1) {     // prefetch next xp row (hides LDS latency)
                    const int sn = s + stp;
                    nz = xp[sn * XP_ST + u]; nr = xp[sn * XP_ST + NU + u]; nh = xp[sn * XP_ST + 2 * NU + u];
                }
                v2f az = v2f{0.f, 0.f}, ar = v2f{0.f, 0.f}, ah = v2f{0.f, 0.f};
                #pragma unroll
                for (int jj = 0; jj < 8; ++jj) {
                    pkfma(az, h2r[jj], wz2[jj]);
                    pkfma(ar, h2r[jj], wr2[jj]);
                    pkfma(ah, h2r[jj], wh2[jj]);
                }
                float rz = az.x + az.y, rr = ar.x + ar.y, rh = ah.x + ah.y;
                rz += __shfl_xor(rz, 32);
                rr += __shfl_xor(rr, 32);
                rh += __shfl_xor(rh, 32);
                const float z  = sigmoidf_(xz + rz + rbz);
                const float r  = sigmoidf_(xr + rr + rbr);
                const float hh = tanhf_(xh + r * (rh + rbh));
                const float hn = hh + z * (h_own - hh);
                hb[u] = hn;                              // both halves write same value (free)
                seqb[s * SEQ_ST + dir * NU + u] = hn;
                const float4* hbp = (const float4*)(hb + half * 16);
                #pragma unroll
                for (int i = 0; i < 4; ++i) {
                    float4 f = hbp[i];
                    h2r[2 * i]     = v2f{f.x, f.y};
                    h2r[2 * i + 1] = v2f{f.z, f.w};
                }
                h_own = hn;
                s += stp; xz = nz; xr = nr; xh = nh;
            }
        }
        __syncthreads();
    }

    // ---- classifier (hbf/hbb hold final h1/h2 from the last scan step) ----
    if (t == 0) {
        float l0 = b_cls[0], l1 = b_cls[1];
        for (int j = 0; j < NU; ++j) {
            const float hf = hbf[j], hk = hbb[j];
            l0 += hf * W_cls[4 * j]     + hk * W_cls[4 * j + 2];
            l1 += hf * W_cls[4 * j + 1] + hk * W_cls[4 * j + 3];
        }
        const float m = fmaxf(l0, l1);
        const float e0 = __expf(l0 - m), e1 = __expf(l1 - m);
        const float inv = 1.0f / (e0 + e1);
        out[b * 2 + 0] = e0 * inv;
        out[b * 2 + 1] = e1 * inv;
    }
}

extern "C" void kernel_launch(void* const* d_in, const int* in_sizes, int n_in,
                              void* d_out, int out_size, void* d_ws, size_t ws_size,
                              hipStream_t stream) {
    const float* xs    = (const float*)d_in[0];
    const float* W_lin = (const float*)d_in[1];
    const float* b_lin = (const float*)d_in[2];
    const float* ln_g  = (const float*)d_in[3];
    const float* ln_b  = (const float*)d_in[4];
    const float* Wk_f  = (const float*)d_in[5];
    const float* Wr_f  = (const float*)d_in[6];
    const float* b_f   = (const float*)d_in[7];
    const float* Wk_b  = (const float*)d_in[8];
    const float* Wr_b  = (const float*)d_in[9];
    const float* b_b   = (const float*)d_in[10];
    const float* W_cls = (const float*)d_in[11];
    const float* b_cls = (const float*)d_in[12];
    float* out = (float*)d_out;

    float* lin_all = (float*)d_ws;   // 13*4096*64 f32 = 13,631,488 B

    const int smem = (S_ * SEQ_ST + 2 * S_ * XP_ST + 64) * (int)sizeof(float);  // 137,472 B
    (void)hipFuncSetAttribute((const void*)chain_kernel,
                              hipFuncAttributeMaxDynamicSharedMemorySize, smem);

    lin_kernel<<<(L_ * B_ * S_) / 64, 256, 0, stream>>>(xs, W_lin, b_lin, lin_all);

    chain_kernel<<<B_, 512, smem, stream>>>(
        lin_all, Wr_f, b_f, Wr_b, b_b, Wk_f, Wk_b, ln_g, ln_b, W_cls, b_cls, out);
}